// Round 1
// baseline (319.608 us; speedup 1.0000x reference)
//
#include <hip/hip_runtime.h>
#include <hip/hip_bf16.h>
#include <cstdint>
#include <cstddef>

#define S_LEN 2048
#define DMODEL 1024
#define NHEAD 16
#define HDK 64
#define LOG2E 1.44269504088896340736f

typedef __attribute__((ext_vector_type(8))) __bf16 bf16x8;
typedef __attribute__((ext_vector_type(4))) __bf16 bf16x4;
typedef __attribute__((ext_vector_type(4))) float f32x4;

#define MFMA16(a, b, c) __builtin_amdgcn_mfma_f32_16x16x32_bf16((a), (b), (c), 0, 0, 0)

// element-offset swizzle for [rows][32] bf16 tiles (row = 64B): permutes the four
// 16B slots of a row by ((row>>1)&3) -> balanced banks for the MFMA frag reads.
__device__ __forceinline__ int swz32(int row, int slot) {
  return row * 32 + ((slot ^ ((row >> 1) & 3)) << 3);
}

// ---------------- f32 -> bf16 convert ----------------
__global__ __launch_bounds__(256) void k_cvt(const float* __restrict__ src,
                                             __bf16* __restrict__ dst, int n4) {
  const int i = blockIdx.x * 256 + threadIdx.x;
  if (i >= n4) return;
  const float4 v = reinterpret_cast<const float4*>(src)[i];
  bf16x4 o = { (__bf16)v.x, (__bf16)v.y, (__bf16)v.z, (__bf16)v.w };
  reinterpret_cast<bf16x4*>(dst)[i] = o;
}

// ---------------- fused QKV projection + RoPE ----------------
// C[m][e] = sum_d X[m][d] * W[e][d]   (einsum 'bsd,ed->bse')
// z=0: Q (rope, [b][h][s][dk])  z=1: K (rope, same)  z=2: V (no rope, [b][h][dk][s])
__global__ __launch_bounds__(256) void k_qkv(
    const __bf16* __restrict__ Xb,
    const __bf16* __restrict__ Wqb, const __bf16* __restrict__ Wkb,
    const __bf16* __restrict__ Wvb, const int* __restrict__ tpos,
    __bf16* __restrict__ Qr, __bf16* __restrict__ Kr, __bf16* __restrict__ Vt) {
  const int z = blockIdx.z;
  const __bf16* W = (z == 0) ? Wqb : (z == 1) ? Wkb : Wvb;
  const int m0 = blockIdx.x * 64;
  const int n0 = blockIdx.y * 64;
  const int t = threadIdx.x;
  const int lane = t & 63;
  const int w = t >> 6;
  const int wm = (w >> 1) * 32;
  const int wn = (w & 1) * 32;
  const int l15 = lane & 15, lhi = lane >> 4;

  __shared__ __align__(16) __bf16 As[64 * 32];
  __shared__ __align__(16) __bf16 Bs[64 * 32];

  const f32x4 z4 = {0.f, 0.f, 0.f, 0.f};
  f32x4 acc[2][2] = {{z4, z4}, {z4, z4}};

  const __bf16* gA = Xb + (size_t)(m0 + (t >> 2)) * DMODEL + (t & 3) * 8;
  const __bf16* gB = W + (size_t)(n0 + (t >> 2)) * DMODEL + (t & 3) * 8;
  const int wr = swz32(t >> 2, t & 3);
  const int a0o = swz32(wm + l15, lhi), a1o = swz32(wm + 16 + l15, lhi);
  const int b0o = swz32(wn + l15, lhi), b1o = swz32(wn + 16 + l15, lhi);

  for (int k0 = 0; k0 < DMODEL; k0 += 32) {
    const bf16x8 ta = *reinterpret_cast<const bf16x8*>(gA + k0);
    const bf16x8 tb = *reinterpret_cast<const bf16x8*>(gB + k0);
    __syncthreads();
    *reinterpret_cast<bf16x8*>(&As[wr]) = ta;
    *reinterpret_cast<bf16x8*>(&Bs[wr]) = tb;
    __syncthreads();
    const bf16x8 a0 = *reinterpret_cast<const bf16x8*>(&As[a0o]);
    const bf16x8 a1 = *reinterpret_cast<const bf16x8*>(&As[a1o]);
    const bf16x8 b0 = *reinterpret_cast<const bf16x8*>(&Bs[b0o]);
    const bf16x8 b1 = *reinterpret_cast<const bf16x8*>(&Bs[b1o]);
    acc[0][0] = MFMA16(a0, b0, acc[0][0]);
    acc[0][1] = MFMA16(a0, b1, acc[0][1]);
    acc[1][0] = MFMA16(a1, b0, acc[1][0]);
    acc[1][1] = MFMA16(a1, b1, acc[1][1]);
  }

  const int b0r = m0 + wm;
#pragma unroll
  for (int mi = 0; mi < 2; ++mi) {
#pragma unroll
    for (int ni = 0; ni < 2; ++ni) {
      const int e = n0 + wn + ni * 16 + l15;
      const int h = e >> 6, dkI = e & 63;
      if (z < 2) {
        // RoPE: pair (2i, 2i+1), ang = pos * theta^(-2i/64)
        const float invf = exp2f(-(float)(dkI & ~1) * (13.287712379549449f / 64.0f));
        __bf16* Out = (z == 0) ? Qr : Kr;
#pragma unroll
        for (int r = 0; r < 4; ++r) {
          const int m = b0r + mi * 16 + lhi * 4 + r;
          const int bb = m >> 11, ss = m & (S_LEN - 1);
          const float pos = (float)tpos[m];
          const float ang = pos * invf;
          const float cs = cosf(ang), sn = sinf(ang);
          const float own = acc[mi][ni][r];
          const float par = __shfl_xor(own, 1);
          const float val = (dkI & 1) ? (par * sn + own * cs) : (own * cs - par * sn);
          Out[(((size_t)bb * NHEAD + h) * S_LEN + ss) * HDK + dkI] = (__bf16)val;
        }
      } else {
#pragma unroll
        for (int r = 0; r < 4; ++r) {
          const int m = b0r + mi * 16 + lhi * 4 + r;
          const int bb = m >> 11, ss = m & (S_LEN - 1);
          Vt[(((size_t)bb * NHEAD + h) * HDK + dkI) * S_LEN + ss] = (__bf16)acc[mi][ni][r];
        }
      }
    }
  }
}

// ---------------- causal flash attention ----------------
// 1 wave per 16 q-rows. QK^T: A=Q rows, B=K rows (both contiguous 16B frags).
// PV: A=P (LDS transpose), B=V from transposed Vt (contiguous 16B frags).
__global__ __launch_bounds__(256) void k_attn(
    const __bf16* __restrict__ Qr, const __bf16* __restrict__ Kr,
    const __bf16* __restrict__ Vt, __bf16* __restrict__ Ob) {
  const int t = threadIdx.x, lane = t & 63, w = t >> 6;
  const int blk = blockIdx.x;
  const int bh = blk >> 5;          // 32 blocks per (b,h)
  const int qg = blk & 31;
  const int q0 = (qg * 4 + w) * 16;
  const int l15 = lane & 15, lhi = lane >> 4;

  const __bf16* Q = Qr + (size_t)bh * S_LEN * HDK;
  const __bf16* K = Kr + (size_t)bh * S_LEN * HDK;
  const __bf16* V = Vt + (size_t)bh * HDK * S_LEN;

  __shared__ __align__(16) __bf16 Plds[4][16 * 32];
  __bf16* Pl = Plds[w];

  const bf16x8 qf0 = *reinterpret_cast<const bf16x8*>(&Q[(size_t)(q0 + l15) * HDK + lhi * 8]);
  const bf16x8 qf1 = *reinterpret_cast<const bf16x8*>(&Q[(size_t)(q0 + l15) * HDK + 32 + lhi * 8]);

  const f32x4 z4 = {0.f, 0.f, 0.f, 0.f};
  f32x4 acc[4] = {z4, z4, z4, z4};
  float mrow[4], lrow[4];
#pragma unroll
  for (int r = 0; r < 4; ++r) { mrow[r] = -1e30f; lrow[r] = 0.0f; }

  const int kmax = q0 + 16;
  for (int k0 = 0; k0 < kmax; k0 += 32) {
    const __bf16* Kp = K + (size_t)(k0 + l15) * HDK + lhi * 8;
    const bf16x8 kf00 = *reinterpret_cast<const bf16x8*>(Kp);
    const bf16x8 kf01 = *reinterpret_cast<const bf16x8*>(Kp + 32);
    const bf16x8 kf10 = *reinterpret_cast<const bf16x8*>(Kp + 16 * HDK);
    const bf16x8 kf11 = *reinterpret_cast<const bf16x8*>(Kp + 16 * HDK + 32);
    f32x4 s0 = z4, s1 = z4;
    s0 = MFMA16(qf0, kf00, s0);
    s0 = MFMA16(qf1, kf01, s0);
    s1 = MFMA16(qf0, kf10, s1);
    s1 = MFMA16(qf1, kf11, s1);

    const bool maskIt = (k0 + 31 > q0);
    float p0[4], p1[4];
#pragma unroll
    for (int r = 0; r < 4; ++r) {
      float a0 = s0[r] * 0.125f;
      float a1 = s1[r] * 0.125f;
      if (maskIt) {
        const int q = q0 + lhi * 4 + r;
        if (k0 + l15 > q) a0 = -1e30f;
        if (k0 + 16 + l15 > q) a1 = -1e30f;
      }
      float mx = fmaxf(a0, a1);
      mx = fmaxf(mx, __shfl_xor(mx, 1));
      mx = fmaxf(mx, __shfl_xor(mx, 2));
      mx = fmaxf(mx, __shfl_xor(mx, 4));
      mx = fmaxf(mx, __shfl_xor(mx, 8));
      const float mn = fmaxf(mrow[r], mx);
      const float sc = exp2f((mrow[r] - mn) * LOG2E);
      a0 = exp2f((a0 - mn) * LOG2E);
      a1 = exp2f((a1 - mn) * LOG2E);
      float rs = a0 + a1;
      rs += __shfl_xor(rs, 1);
      rs += __shfl_xor(rs, 2);
      rs += __shfl_xor(rs, 4);
      rs += __shfl_xor(rs, 8);
      lrow[r] = lrow[r] * sc + rs;
      mrow[r] = mn;
      p0[r] = a0;
      p1[r] = a1;
#pragma unroll
      for (int dt = 0; dt < 4; ++dt) acc[dt][r] *= sc;
    }

    // transpose P through per-wave LDS (swizzled); no block barrier (divergent trips)
#pragma unroll
    for (int r = 0; r < 4; ++r) {
      const int row = lhi * 4 + r;
      const int c0 = l15;
      const int c1 = 16 + l15;
      Pl[row * 32 + ((((c0 >> 3) ^ ((row >> 1) & 3)) << 3)) + (c0 & 7)] = (__bf16)p0[r];
      Pl[row * 32 + ((((c1 >> 3) ^ ((row >> 1) & 3)) << 3)) + (c1 & 7)] = (__bf16)p1[r];
    }
    asm volatile("s_waitcnt lgkmcnt(0)" ::: "memory");
    __builtin_amdgcn_sched_barrier(0);
    const bf16x8 pa = *reinterpret_cast<const bf16x8*>(&Pl[swz32(l15, lhi)]);

    const __bf16* Vp = V + (size_t)l15 * S_LEN + k0 + lhi * 8;
#pragma unroll
    for (int dt = 0; dt < 4; ++dt) {
      const bf16x8 vf = *reinterpret_cast<const bf16x8*>(Vp + (size_t)dt * 16 * S_LEN);
      acc[dt] = MFMA16(pa, vf, acc[dt]);
    }
  }

  const int b = bh >> 4, h = bh & 15;
#pragma unroll
  for (int dt = 0; dt < 4; ++dt) {
#pragma unroll
    for (int r = 0; r < 4; ++r) {
      const int q = q0 + lhi * 4 + r;
      const float o = acc[dt][r] / lrow[r];
      Ob[((size_t)(b * S_LEN + q)) * DMODEL + h * HDK + dt * 16 + l15] = (__bf16)o;
    }
  }
}

// ---------------- output projection (f32 out) ----------------
__global__ __launch_bounds__(256) void k_oproj(
    const __bf16* __restrict__ Ob, const __bf16* __restrict__ Wob,
    float* __restrict__ out) {
  const int m0 = blockIdx.x * 64;
  const int n0 = blockIdx.y * 64;
  const int t = threadIdx.x;
  const int lane = t & 63;
  const int w = t >> 6;
  const int wm = (w >> 1) * 32;
  const int wn = (w & 1) * 32;
  const int l15 = lane & 15, lhi = lane >> 4;

  __shared__ __align__(16) __bf16 As[64 * 32];
  __shared__ __align__(16) __bf16 Bs[64 * 32];

  const f32x4 z4 = {0.f, 0.f, 0.f, 0.f};
  f32x4 acc[2][2] = {{z4, z4}, {z4, z4}};

  const __bf16* gA = Ob + (size_t)(m0 + (t >> 2)) * DMODEL + (t & 3) * 8;
  const __bf16* gB = Wob + (size_t)(n0 + (t >> 2)) * DMODEL + (t & 3) * 8;
  const int wr = swz32(t >> 2, t & 3);
  const int a0o = swz32(wm + l15, lhi), a1o = swz32(wm + 16 + l15, lhi);
  const int b0o = swz32(wn + l15, lhi), b1o = swz32(wn + 16 + l15, lhi);

  for (int k0 = 0; k0 < DMODEL; k0 += 32) {
    const bf16x8 ta = *reinterpret_cast<const bf16x8*>(gA + k0);
    const bf16x8 tb = *reinterpret_cast<const bf16x8*>(gB + k0);
    __syncthreads();
    *reinterpret_cast<bf16x8*>(&As[wr]) = ta;
    *reinterpret_cast<bf16x8*>(&Bs[wr]) = tb;
    __syncthreads();
    const bf16x8 a0 = *reinterpret_cast<const bf16x8*>(&As[a0o]);
    const bf16x8 a1 = *reinterpret_cast<const bf16x8*>(&As[a1o]);
    const bf16x8 b0 = *reinterpret_cast<const bf16x8*>(&Bs[b0o]);
    const bf16x8 b1 = *reinterpret_cast<const bf16x8*>(&Bs[b1o]);
    acc[0][0] = MFMA16(a0, b0, acc[0][0]);
    acc[0][1] = MFMA16(a0, b1, acc[0][1]);
    acc[1][0] = MFMA16(a1, b0, acc[1][0]);
    acc[1][1] = MFMA16(a1, b1, acc[1][1]);
  }

#pragma unroll
  for (int mi = 0; mi < 2; ++mi) {
#pragma unroll
    for (int ni = 0; ni < 2; ++ni) {
      const int e = n0 + wn + ni * 16 + l15;
#pragma unroll
      for (int r = 0; r < 4; ++r) {
        const int m = m0 + wm + mi * 16 + lhi * 4 + r;
        out[(size_t)m * DMODEL + e] = acc[mi][ni][r];
      }
    }
  }
}

extern "C" void kernel_launch(void* const* d_in, const int* in_sizes, int n_in,
                              void* d_out, int out_size, void* d_ws, size_t ws_size,
                              hipStream_t stream) {
  const float* x = (const float*)d_in[0];
  const int* tpos = (const int*)d_in[1];
  const float* Wq = (const float*)d_in[2];
  const float* Wk = (const float*)d_in[3];
  const float* Wv = (const float*)d_in[4];
  const float* Wo = (const float*)d_in[5];
  float* out = (float*)d_out;

  __bf16* ws = (__bf16*)d_ws;
  __bf16* Xb = ws;                    // 4096x1024
  __bf16* Wqb = Xb + 4194304;         // 1024x1024
  __bf16* Wkb = Wqb + 1048576;
  __bf16* Wvb = Wkb + 1048576;
  __bf16* Wob = Wvb + 1048576;
  __bf16* Qr = Wob + 1048576;         // [2][16][2048][64]
  __bf16* Kr = Qr + 4194304;
  __bf16* Vt = Kr + 4194304;          // [2][16][64][2048]
  __bf16* Ob = Vt + 4194304;          // 4096x1024

  k_cvt<<<4096, 256, 0, stream>>>(x, Xb, 1048576);
  k_cvt<<<1024, 256, 0, stream>>>(Wq, Wqb, 262144);
  k_cvt<<<1024, 256, 0, stream>>>(Wk, Wkb, 262144);
  k_cvt<<<1024, 256, 0, stream>>>(Wv, Wvb, 262144);
  k_cvt<<<1024, 256, 0, stream>>>(Wo, Wob, 262144);

  dim3 g1(64, 16, 3);
  k_qkv<<<g1, 256, 0, stream>>>(Xb, Wqb, Wkb, Wvb, tpos, Qr, Kr, Vt);

  k_attn<<<1024, 256, 0, stream>>>(Qr, Kr, Vt, Ob);

  dim3 g2(64, 16);
  k_oproj<<<g2, 256, 0, stream>>>(Ob, Wob, out);
}

// Round 3
// 236.520 us; speedup vs baseline: 1.3513x; 1.3513x over previous
//
#include <hip/hip_runtime.h>
#include <hip/hip_bf16.h>
#include <cstdint>
#include <cstddef>

#define S_LEN 2048
#define DMODEL 1024
#define NHEAD 16
#define HDK 64
#define LOG2E 1.44269504088896340736f

typedef __attribute__((ext_vector_type(8))) __bf16 bf16x8;
typedef __attribute__((ext_vector_type(4))) __bf16 bf16x4;
typedef __attribute__((ext_vector_type(4))) float f32x4;

#define MFMA16(a, b, c) __builtin_amdgcn_mfma_f32_16x16x32_bf16((a), (b), (c), 0, 0, 0)

// element-offset swizzle for [rows][32] bf16 tiles (row = 64B): permutes the four
// 16B slots of a row by ((row>>1)&3) -> balanced banks for the MFMA frag reads.
__device__ __forceinline__ int swz32(int row, int slot) {
  return row * 32 + ((slot ^ ((row >> 1) & 3)) << 3);
}

// ---------------- f32 -> bf16 convert ----------------
__global__ __launch_bounds__(256) void k_cvt(const float* __restrict__ src,
                                             __bf16* __restrict__ dst, int n4) {
  const int i = blockIdx.x * 256 + threadIdx.x;
  if (i >= n4) return;
  const float4 v = reinterpret_cast<const float4*>(src)[i];
  bf16x4 o = { (__bf16)v.x, (__bf16)v.y, (__bf16)v.z, (__bf16)v.w };
  reinterpret_cast<bf16x4*>(dst)[i] = o;
}

// ---------------- fused QKV projection + RoPE ----------------
// C[m][e] = sum_d X[m][d] * W[e][d]   (einsum 'bsd,ed->bse')
// z=0: Q (rope, [b][h][s][dk])  z=1: K (rope, same)  z=2: V (no rope, [b][h][dk][s])
__global__ __launch_bounds__(256) void k_qkv(
    const __bf16* __restrict__ Xb,
    const __bf16* __restrict__ Wqb, const __bf16* __restrict__ Wkb,
    const __bf16* __restrict__ Wvb, const int* __restrict__ tpos,
    __bf16* __restrict__ Qr, __bf16* __restrict__ Kr, __bf16* __restrict__ Vt) {
  const int z = blockIdx.z;
  const __bf16* W = (z == 0) ? Wqb : (z == 1) ? Wkb : Wvb;
  const int m0 = blockIdx.x * 64;
  const int n0 = blockIdx.y * 64;
  const int t = threadIdx.x;
  const int lane = t & 63;
  const int w = t >> 6;
  const int wm = (w >> 1) * 32;
  const int wn = (w & 1) * 32;
  const int l15 = lane & 15, lhi = lane >> 4;

  __shared__ __align__(16) __bf16 As[64 * 32];
  __shared__ __align__(16) __bf16 Bs[64 * 32];

  const f32x4 z4 = {0.f, 0.f, 0.f, 0.f};
  f32x4 acc[2][2] = {{z4, z4}, {z4, z4}};

  const __bf16* gA = Xb + (size_t)(m0 + (t >> 2)) * DMODEL + (t & 3) * 8;
  const __bf16* gB = W + (size_t)(n0 + (t >> 2)) * DMODEL + (t & 3) * 8;
  const int wr = swz32(t >> 2, t & 3);
  const int a0o = swz32(wm + l15, lhi), a1o = swz32(wm + 16 + l15, lhi);
  const int b0o = swz32(wn + l15, lhi), b1o = swz32(wn + 16 + l15, lhi);

  for (int k0 = 0; k0 < DMODEL; k0 += 32) {
    const bf16x8 ta = *reinterpret_cast<const bf16x8*>(gA + k0);
    const bf16x8 tb = *reinterpret_cast<const bf16x8*>(gB + k0);
    __syncthreads();
    *reinterpret_cast<bf16x8*>(&As[wr]) = ta;
    *reinterpret_cast<bf16x8*>(&Bs[wr]) = tb;
    __syncthreads();
    const bf16x8 a0 = *reinterpret_cast<const bf16x8*>(&As[a0o]);
    const bf16x8 a1 = *reinterpret_cast<const bf16x8*>(&As[a1o]);
    const bf16x8 b0 = *reinterpret_cast<const bf16x8*>(&Bs[b0o]);
    const bf16x8 b1 = *reinterpret_cast<const bf16x8*>(&Bs[b1o]);
    acc[0][0] = MFMA16(a0, b0, acc[0][0]);
    acc[0][1] = MFMA16(a0, b1, acc[0][1]);
    acc[1][0] = MFMA16(a1, b0, acc[1][0]);
    acc[1][1] = MFMA16(a1, b1, acc[1][1]);
  }

  const int b0r = m0 + wm;
#pragma unroll
  for (int mi = 0; mi < 2; ++mi) {
#pragma unroll
    for (int ni = 0; ni < 2; ++ni) {
      const int e = n0 + wn + ni * 16 + l15;
      const int h = e >> 6, dkI = e & 63;
      if (z < 2) {
        // RoPE: pair (2i, 2i+1), ang = pos * theta^(-2i/64)
        const float invf = exp2f(-(float)(dkI & ~1) * (13.287712379549449f / 64.0f));
        __bf16* Out = (z == 0) ? Qr : Kr;
#pragma unroll
        for (int r = 0; r < 4; ++r) {
          const int m = b0r + mi * 16 + lhi * 4 + r;
          const int bb = m >> 11, ss = m & (S_LEN - 1);
          const float pos = (float)tpos[m];
          const float ang = pos * invf;
          const float cs = cosf(ang), sn = sinf(ang);
          const float own = acc[mi][ni][r];
          const float par = __shfl_xor(own, 1);
          const float val = (dkI & 1) ? (par * sn + own * cs) : (own * cs - par * sn);
          Out[(((size_t)bb * NHEAD + h) * S_LEN + ss) * HDK + dkI] = (__bf16)val;
        }
      } else {
#pragma unroll
        for (int r = 0; r < 4; ++r) {
          const int m = b0r + mi * 16 + lhi * 4 + r;
          const int bb = m >> 11, ss = m & (S_LEN - 1);
          Vt[(((size_t)bb * NHEAD + h) * HDK + dkI) * S_LEN + ss] = (__bf16)acc[mi][ni][r];
        }
      }
    }
  }
}

// ---------------- causal flash attention (swapped-QK^T, KBLK=64) ----------------
// 1 wave per 16 q-rows. S^T = mfma(K, Q): lane holds q=lane&15, k=f*16+(lane>>4)*4+r
// -> row-max/sum is 15 in-reg fmax + 2 shfl. Softmax stats are indexed by q=l15;
// the PV accumulator rows are q=(lane>>4)*4+r -> the rescale factor must be
// SHUFFLED across that mapping (sc is lhi-uniform, so lane lhi*4+r holds query
// lhi*4+r's value). P transpose via per-wave swizzled LDS. PV: A=P, B=V^T frags.
__global__ __launch_bounds__(256) void k_attn(
    const __bf16* __restrict__ Qr, const __bf16* __restrict__ Kr,
    const __bf16* __restrict__ Vt, __bf16* __restrict__ Ob) {
  const int t = threadIdx.x, lane = t & 63, w = t >> 6;
  const int blk = blockIdx.x;
  const int qg = blk >> 5;        // 0..31 (q-group major: heavy groups dispatch first)
  const int bh = blk & 31;
  const int qtile = (31 - qg) * 4 + w;   // 0..127, heavy-first
  const int q0 = qtile * 16;
  const int l15 = lane & 15, lhi = lane >> 4;

  const __bf16* Q = Qr + (size_t)bh * (S_LEN * HDK);
  const __bf16* K = Kr + (size_t)bh * (S_LEN * HDK);
  const __bf16* V = Vt + (size_t)bh * (HDK * S_LEN);

  __shared__ __align__(16) __bf16 Plds[4][16 * 64];   // per-wave 2KB P^T buffer
  __bf16* Pl = Plds[w];

  const bf16x8 qf0 = *reinterpret_cast<const bf16x8*>(&Q[(size_t)(q0 + l15) * HDK + lhi * 8]);
  const bf16x8 qf1 = *reinterpret_cast<const bf16x8*>(&Q[(size_t)(q0 + l15) * HDK + 32 + lhi * 8]);

  const f32x4 z4 = {0.f, 0.f, 0.f, 0.f};
  f32x4 acc[4] = {z4, z4, z4, z4};
  float m_run = -3e30f, l_run = 0.0f;

  const int swzkey = (l15 & 7) << 3;   // XOR key, 8-elem (16B) granularity
  const int q = q0 + l15;
  const int kmax = q0 + 16;

  for (int k0 = 0; k0 < kmax; k0 += 64) {
    // ---- QK^T (swapped): S^T[k][q], 4 frags of 16 k-rows ----
    f32x4 sT[4];
#pragma unroll
    for (int f = 0; f < 4; ++f) {
      const __bf16* Kp = &K[(size_t)(k0 + f * 16 + l15) * HDK + lhi * 8];
      const bf16x8 ka = *reinterpret_cast<const bf16x8*>(Kp);
      const bf16x8 kb = *reinterpret_cast<const bf16x8*>(Kp + 32);
      sT[f] = MFMA16(ka, qf0, z4);
      sT[f] = MFMA16(kb, qf1, sT[f]);
    }

    // ---- scale + causal mask + in-register row max ----
    const bool maskIt = (k0 + 63 > q0);
    float sv[4][4];
    float mx = -3e30f;
#pragma unroll
    for (int f = 0; f < 4; ++f) {
#pragma unroll
      for (int r = 0; r < 4; ++r) {
        float s = sT[f][r] * 0.125f;
        if (maskIt && (k0 + f * 16 + lhi * 4 + r > q)) s = -3e30f;
        sv[f][r] = s;
        mx = fmaxf(mx, s);
      }
    }
    mx = fmaxf(mx, __shfl_xor(mx, 16));
    mx = fmaxf(mx, __shfl_xor(mx, 32));
    const float mn = fmaxf(m_run, mx);
    const float sc = exp2f((m_run - mn) * LOG2E);
    m_run = mn;

    // ---- exp, running sum, pack to bf16, write P^T to LDS ----
    float rs = 0.0f;
#pragma unroll
    for (int f = 0; f < 4; ++f) {
      const float p0 = exp2f((sv[f][0] - mn) * LOG2E);
      const float p1 = exp2f((sv[f][1] - mn) * LOG2E);
      const float p2 = exp2f((sv[f][2] - mn) * LOG2E);
      const float p3 = exp2f((sv[f][3] - mn) * LOG2E);
      rs += (p0 + p1) + (p2 + p3);
      bf16x4 pk = { (__bf16)p0, (__bf16)p1, (__bf16)p2, (__bf16)p3 };
      *reinterpret_cast<bf16x4*>(&Pl[l15 * 64 + ((f * 16 + lhi * 4) ^ swzkey)]) = pk;
    }
    rs += __shfl_xor(rs, 16);
    rs += __shfl_xor(rs, 32);
    l_run = l_run * sc + rs;

    // ---- rescale accumulator: acc rows are q=lhi*4+r, sc is indexed by q=l15.
    // sc is uniform across the lhi group, so lane (lhi*4+r) holds query
    // (lhi*4+r)'s sc -> broadcast via shfl. ----
    float scA[4];
#pragma unroll
    for (int r = 0; r < 4; ++r) scA[r] = __shfl(sc, lhi * 4 + r);
#pragma unroll
    for (int dt = 0; dt < 4; ++dt) {
#pragma unroll
      for (int r = 0; r < 4; ++r) acc[dt][r] *= scA[r];
    }

    // per-wave LDS buffer: wave-local drain, no block barrier
    asm volatile("s_waitcnt lgkmcnt(0)" ::: "memory");
    __builtin_amdgcn_sched_barrier(0);

    // ---- PV: 2 k-chunks of 32 ----
#pragma unroll
    for (int c = 0; c < 2; ++c) {
      const bf16x8 pa = *reinterpret_cast<const bf16x8*>(
          &Pl[l15 * 64 + ((c * 32 + lhi * 8) ^ swzkey)]);
      const __bf16* Vp = &V[(size_t)l15 * S_LEN + k0 + c * 32 + lhi * 8];
#pragma unroll
      for (int dt = 0; dt < 4; ++dt) {
        const bf16x8 vf = *reinterpret_cast<const bf16x8*>(Vp + (size_t)dt * 16 * S_LEN);
        acc[dt] = MFMA16(pa, vf, acc[dt]);
      }
    }
  }

  // ---- epilogue: normalize (l indexed by q=l15; output rows are lhi*4+r) ----
  const int b = bh >> 4, h = bh & 15;
#pragma unroll
  for (int r = 0; r < 4; ++r) {
    const float lq = __shfl(l_run, lhi * 4 + r);
    const float inv = 1.0f / lq;
    const int qo = q0 + lhi * 4 + r;
#pragma unroll
    for (int dt = 0; dt < 4; ++dt) {
      Ob[((size_t)(b * S_LEN + qo)) * DMODEL + h * HDK + dt * 16 + l15] =
          (__bf16)(acc[dt][r] * inv);
    }
  }
}

// ---------------- output projection (f32 out) ----------------
__global__ __launch_bounds__(256) void k_oproj(
    const __bf16* __restrict__ Ob, const __bf16* __restrict__ Wob,
    float* __restrict__ out) {
  const int m0 = blockIdx.x * 64;
  const int n0 = blockIdx.y * 64;
  const int t = threadIdx.x;
  const int lane = t & 63;
  const int w = t >> 6;
  const int wm = (w >> 1) * 32;
  const int wn = (w & 1) * 32;
  const int l15 = lane & 15, lhi = lane >> 4;

  __shared__ __align__(16) __bf16 As[64 * 32];
  __shared__ __align__(16) __bf16 Bs[64 * 32];

  const f32x4 z4 = {0.f, 0.f, 0.f, 0.f};
  f32x4 acc[2][2] = {{z4, z4}, {z4, z4}};

  const __bf16* gA = Ob + (size_t)(m0 + (t >> 2)) * DMODEL + (t & 3) * 8;
  const __bf16* gB = Wob + (size_t)(n0 + (t >> 2)) * DMODEL + (t & 3) * 8;
  const int wr = swz32(t >> 2, t & 3);
  const int a0o = swz32(wm + l15, lhi), a1o = swz32(wm + 16 + l15, lhi);
  const int b0o = swz32(wn + l15, lhi), b1o = swz32(wn + 16 + l15, lhi);

  for (int k0 = 0; k0 < DMODEL; k0 += 32) {
    const bf16x8 ta = *reinterpret_cast<const bf16x8*>(gA + k0);
    const bf16x8 tb = *reinterpret_cast<const bf16x8*>(gB + k0);
    __syncthreads();
    *reinterpret_cast<bf16x8*>(&As[wr]) = ta;
    *reinterpret_cast<bf16x8*>(&Bs[wr]) = tb;
    __syncthreads();
    const bf16x8 a0 = *reinterpret_cast<const bf16x8*>(&As[a0o]);
    const bf16x8 a1 = *reinterpret_cast<const bf16x8*>(&As[a1o]);
    const bf16x8 b0 = *reinterpret_cast<const bf16x8*>(&Bs[b0o]);
    const bf16x8 b1 = *reinterpret_cast<const bf16x8*>(&Bs[b1o]);
    acc[0][0] = MFMA16(a0, b0, acc[0][0]);
    acc[0][1] = MFMA16(a0, b1, acc[0][1]);
    acc[1][0] = MFMA16(a1, b0, acc[1][0]);
    acc[1][1] = MFMA16(a1, b1, acc[1][1]);
  }

#pragma unroll
  for (int mi = 0; mi < 2; ++mi) {
#pragma unroll
    for (int ni = 0; ni < 2; ++ni) {
      const int e = n0 + wn + ni * 16 + l15;
#pragma unroll
      for (int r = 0; r < 4; ++r) {
        const int m = m0 + wm + mi * 16 + lhi * 4 + r;
        out[(size_t)m * DMODEL + e] = acc[mi][ni][r];
      }
    }
  }
}

extern "C" void kernel_launch(void* const* d_in, const int* in_sizes, int n_in,
                              void* d_out, int out_size, void* d_ws, size_t ws_size,
                              hipStream_t stream) {
  const float* x = (const float*)d_in[0];
  const int* tpos = (const int*)d_in[1];
  const float* Wq = (const float*)d_in[2];
  const float* Wk = (const float*)d_in[3];
  const float* Wv = (const float*)d_in[4];
  const float* Wo = (const float*)d_in[5];
  float* out = (float*)d_out;

  __bf16* ws = (__bf16*)d_ws;
  __bf16* Xb = ws;                    // 4096x1024
  __bf16* Wqb = Xb + 4194304;         // 1024x1024
  __bf16* Wkb = Wqb + 1048576;
  __bf16* Wvb = Wkb + 1048576;
  __bf16* Wob = Wvb + 1048576;
  __bf16* Qr = Wob + 1048576;         // [2][16][2048][64]
  __bf16* Kr = Qr + 4194304;
  __bf16* Vt = Kr + 4194304;          // [2][16][64][2048]
  __bf16* Ob = Vt + 4194304;          // 4096x1024

  k_cvt<<<4096, 256, 0, stream>>>(x, Xb, 1048576);
  k_cvt<<<1024, 256, 0, stream>>>(Wq, Wqb, 262144);
  k_cvt<<<1024, 256, 0, stream>>>(Wk, Wkb, 262144);
  k_cvt<<<1024, 256, 0, stream>>>(Wv, Wvb, 262144);
  k_cvt<<<1024, 256, 0, stream>>>(Wo, Wob, 262144);

  dim3 g1(64, 16, 3);
  k_qkv<<<g1, 256, 0, stream>>>(Xb, Wqb, Wkb, Wvb, tpos, Qr, Kr, Vt);

  k_attn<<<1024, 256, 0, stream>>>(Qr, Kr, Vt, Ob);

  dim3 g2(64, 16);
  k_oproj<<<g2, 256, 0, stream>>>(Ob, Wob, out);
}

// Round 5
// 227.241 us; speedup vs baseline: 1.4065x; 1.0408x over previous
//
#include <hip/hip_runtime.h>
#include <hip/hip_bf16.h>
#include <cstdint>
#include <cstddef>

#define S_LEN 2048
#define DMODEL 1024
#define NHEAD 16
#define HDK 64
#define LOG2E 1.44269504088896340736f

typedef __attribute__((ext_vector_type(8))) __bf16 bf16x8;
typedef __attribute__((ext_vector_type(4))) __bf16 bf16x4;
typedef __attribute__((ext_vector_type(4))) float f32x4;
typedef __attribute__((ext_vector_type(16))) float f32x16;
typedef __attribute__((ext_vector_type(4))) unsigned int u32x4;

#define MFMA16(a, b, c) __builtin_amdgcn_mfma_f32_16x16x32_bf16((a), (b), (c), 0, 0, 0)
#define MFMA32(a, b, c) __builtin_amdgcn_mfma_f32_32x32x16_bf16((a), (b), (c), 0, 0, 0)

// element-offset swizzle for [rows][32] bf16 tiles (row = 64B): permutes the four
// 16B slots of a row by ((row>>1)&3) -> balanced banks for the MFMA frag reads.
__device__ __forceinline__ int swz32(int row, int slot) {
  return row * 32 + ((slot ^ ((row >> 1) & 3)) << 3);
}

// pack two f32 -> one dword of 2 bf16 (lo = first)
__device__ __forceinline__ unsigned pk2(float a, float b) {
  union { __bf16 h[2]; unsigned u; } cv;
  cv.h[0] = (__bf16)a;
  cv.h[1] = (__bf16)b;
  return cv.u;
}

// ---------------- f32 -> bf16 convert ----------------
__global__ __launch_bounds__(256) void k_cvt(const float* __restrict__ src,
                                             __bf16* __restrict__ dst, int n4) {
  const int i = blockIdx.x * 256 + threadIdx.x;
  if (i >= n4) return;
  const float4 v = reinterpret_cast<const float4*>(src)[i];
  bf16x4 o = { (__bf16)v.x, (__bf16)v.y, (__bf16)v.z, (__bf16)v.w };
  reinterpret_cast<bf16x4*>(dst)[i] = o;
}

// ---------------- fused QKV projection + RoPE ----------------
// C[m][e] = sum_d X[m][d] * W[e][d]   (einsum 'bsd,ed->bse')
// z=0: Q (rope, pre-scaled by 1/8, [b][h][s][dk])  z=1: K (rope)  z=2: V ([b][h][dk][s])
__global__ __launch_bounds__(256) void k_qkv(
    const __bf16* __restrict__ Xb,
    const __bf16* __restrict__ Wqb, const __bf16* __restrict__ Wkb,
    const __bf16* __restrict__ Wvb, const int* __restrict__ tpos,
    __bf16* __restrict__ Qr, __bf16* __restrict__ Kr, __bf16* __restrict__ Vt) {
  const int z = blockIdx.z;
  const __bf16* W = (z == 0) ? Wqb : (z == 1) ? Wkb : Wvb;
  const int m0 = blockIdx.x * 64;
  const int n0 = blockIdx.y * 64;
  const int t = threadIdx.x;
  const int lane = t & 63;
  const int w = t >> 6;
  const int wm = (w >> 1) * 32;
  const int wn = (w & 1) * 32;
  const int l15 = lane & 15, lhi = lane >> 4;

  __shared__ __align__(16) __bf16 As[64 * 32];
  __shared__ __align__(16) __bf16 Bs[64 * 32];

  const f32x4 z4 = {0.f, 0.f, 0.f, 0.f};
  f32x4 acc[2][2] = {{z4, z4}, {z4, z4}};

  const __bf16* gA = Xb + (size_t)(m0 + (t >> 2)) * DMODEL + (t & 3) * 8;
  const __bf16* gB = W + (size_t)(n0 + (t >> 2)) * DMODEL + (t & 3) * 8;
  const int wr = swz32(t >> 2, t & 3);
  const int a0o = swz32(wm + l15, lhi), a1o = swz32(wm + 16 + l15, lhi);
  const int b0o = swz32(wn + l15, lhi), b1o = swz32(wn + 16 + l15, lhi);

  for (int k0 = 0; k0 < DMODEL; k0 += 32) {
    const bf16x8 ta = *reinterpret_cast<const bf16x8*>(gA + k0);
    const bf16x8 tb = *reinterpret_cast<const bf16x8*>(gB + k0);
    __syncthreads();
    *reinterpret_cast<bf16x8*>(&As[wr]) = ta;
    *reinterpret_cast<bf16x8*>(&Bs[wr]) = tb;
    __syncthreads();
    const bf16x8 a0 = *reinterpret_cast<const bf16x8*>(&As[a0o]);
    const bf16x8 a1 = *reinterpret_cast<const bf16x8*>(&As[a1o]);
    const bf16x8 b0 = *reinterpret_cast<const bf16x8*>(&Bs[b0o]);
    const bf16x8 b1 = *reinterpret_cast<const bf16x8*>(&Bs[b1o]);
    acc[0][0] = MFMA16(a0, b0, acc[0][0]);
    acc[0][1] = MFMA16(a0, b1, acc[0][1]);
    acc[1][0] = MFMA16(a1, b0, acc[1][0]);
    acc[1][1] = MFMA16(a1, b1, acc[1][1]);
  }

  const int b0r = m0 + wm;
#pragma unroll
  for (int mi = 0; mi < 2; ++mi) {
#pragma unroll
    for (int ni = 0; ni < 2; ++ni) {
      const int e = n0 + wn + ni * 16 + l15;
      const int h = e >> 6, dkI = e & 63;
      if (z < 2) {
        // RoPE: pair (2i, 2i+1), ang = pos * theta^(-2i/64)
        const float invf = exp2f(-(float)(dkI & ~1) * (13.287712379549449f / 64.0f));
        const float oscale = (z == 0) ? 0.125f : 1.0f;  // fold 1/sqrt(dk) into Q
        __bf16* Out = (z == 0) ? Qr : Kr;
#pragma unroll
        for (int r = 0; r < 4; ++r) {
          const int m = b0r + mi * 16 + lhi * 4 + r;
          const int bb = m >> 11, ss = m & (S_LEN - 1);
          const float pos = (float)tpos[m];
          const float ang = pos * invf;
          const float cs = cosf(ang), sn = sinf(ang);
          const float own = acc[mi][ni][r];
          const float par = __shfl_xor(own, 1);
          const float val = (dkI & 1) ? (par * sn + own * cs) : (own * cs - par * sn);
          Out[(((size_t)bb * NHEAD + h) * S_LEN + ss) * HDK + dkI] = (__bf16)(val * oscale);
        }
      } else {
#pragma unroll
        for (int r = 0; r < 4; ++r) {
          const int m = b0r + mi * 16 + lhi * 4 + r;
          const int bb = m >> 11, ss = m & (S_LEN - 1);
          Vt[(((size_t)bb * NHEAD + h) * HDK + dkI) * S_LEN + ss] = (__bf16)acc[mi][ni][r];
        }
      }
    }
  }
}

// ---------------- causal flash attention (QBLK=32, 32x32 MFMA, LDS-free) ----------------
// 1 wave per 32 q-rows. S^T = mfma(K, Q) 32x32x16: lane holds q=lane&31,
// k = (reg&3)+8*(reg>>2)+4*(lane>>5). Row reduce: 31 fmax + 1 shfl_xor(32).
// P -> PV A-frag in-register: lane (q,hi) holds k-pairs {4hi..4hi+3, 8+4hi..8+4hi+3}
// per 16-chunk as dwords pd[base..base+3]; the A-frag needs k=hi*8+j, so frag
// words are a cross-half exchange: w0=hi?x2:a0, w1=hi?x3:a1, w2=hi?a2:x0,
// w3=hi?a3:x1 with xN=shfl_xor(aN,32). (Equivalent to permlane32_swap(w0,w2),
// (w1,w3) — done via shfl_xor+cndmask for semantics certainty.)
// Defer-max: rescale (16 shfl broadcasts) only when max grows > 8.
__global__ __launch_bounds__(256) void k_attn(
    const __bf16* __restrict__ Qr, const __bf16* __restrict__ Kr,
    const __bf16* __restrict__ Vt, __bf16* __restrict__ Ob) {
  const int t = threadIdx.x, lane = t & 63, w = t >> 6;
  const int blk = blockIdx.x;
  const int qg = blk >> 5;               // 0..15, heavy-first
  const int bh = blk & 31;
  const int qtile = (15 - qg) * 4 + w;   // 0..63
  const int q0 = qtile * 32;
  const int l31 = lane & 31, hi = lane >> 5;

  const __bf16* Q = Qr + (size_t)bh * (S_LEN * HDK);
  const __bf16* K = Kr + (size_t)bh * (S_LEN * HDK);
  const __bf16* V = Vt + (size_t)bh * (HDK * S_LEN);

  // Q fragments: row q=l31, d-chunk dc: elements d = dc*16 + hi*8 + j
  bf16x8 qf[4];
#pragma unroll
  for (int dc = 0; dc < 4; ++dc)
    qf[dc] = *reinterpret_cast<const bf16x8*>(
        &Q[(size_t)(q0 + l31) * HDK + dc * 16 + hi * 8]);

  f32x16 accO[2] = {};
  float m_run = -3e30f, l_run = 0.0f;
  const int q = q0 + l31;
  const int kmax = q0 + 32;

  for (int k0 = 0; k0 < kmax; k0 += 64) {
    // ---- QK^T (swapped): two 32k x 32q tiles ----
    f32x16 sT0 = {}, sT1 = {};
    const __bf16* Kp0 = &K[(size_t)(k0 + l31) * HDK + hi * 8];
    const __bf16* Kp1 = Kp0 + 32 * HDK;
#pragma unroll
    for (int dc = 0; dc < 4; ++dc) {
      sT0 = MFMA32(*reinterpret_cast<const bf16x8*>(Kp0 + dc * 16), qf[dc], sT0);
      sT1 = MFMA32(*reinterpret_cast<const bf16x8*>(Kp1 + dc * 16), qf[dc], sT1);
    }

    // ---- causal mask + in-register max ----
    const bool maskIt = (k0 + 63 > q0);
    float mx = -3e30f;
#pragma unroll
    for (int r = 0; r < 16; ++r) {
      float s0 = sT0[r], s1 = sT1[r];
      if (maskIt) {
        const int kb = (r & 3) + ((r >> 2) << 3) + hi * 4;
        if (k0 + kb > q) s0 = -3e30f;
        if (k0 + 32 + kb > q) s1 = -3e30f;
      }
      sT0[r] = s0;
      sT1[r] = s1;
      mx = fmaxf(mx, fmaxf(s0, s1));
    }
    mx = fmaxf(mx, __shfl_xor(mx, 32));

    // ---- defer-max: rescale only when max grew past threshold ----
    float sc = 1.0f;
    if (!__all(mx <= m_run + 8.0f)) {
      const float mn = fmaxf(m_run, mx);
      sc = exp2f((m_run - mn) * LOG2E);
      m_run = mn;
      float scA[16];
#pragma unroll
      for (int r = 0; r < 16; ++r)
        scA[r] = __shfl(sc, (r & 3) + ((r >> 2) << 3) + hi * 4);
#pragma unroll
      for (int dt = 0; dt < 2; ++dt)
#pragma unroll
        for (int r = 0; r < 16; ++r) accO[dt][r] *= scA[r];
    }

    // ---- exp + running sum + pack to bf16 dwords ----
    float rs = 0.0f;
    unsigned pd[16];
#pragma unroll
    for (int j = 0; j < 8; ++j) {
      const float p0 = exp2f((sT0[2 * j] - m_run) * LOG2E);
      const float p1 = exp2f((sT0[2 * j + 1] - m_run) * LOG2E);
      const float p2 = exp2f((sT1[2 * j] - m_run) * LOG2E);
      const float p3 = exp2f((sT1[2 * j + 1] - m_run) * LOG2E);
      rs += (p0 + p1) + (p2 + p3);
      pd[j] = pk2(p0, p1);
      pd[8 + j] = pk2(p2, p3);
    }
    rs += __shfl_xor(rs, 32);
    l_run = l_run * sc + rs;

    // ---- PV: build A-frags via cross-half shfl + select, accumulate ----
#pragma unroll
    for (int tt = 0; tt < 2; ++tt) {
#pragma unroll
      for (int c = 0; c < 2; ++c) {
        const int base = tt * 8 + c * 4;
        const unsigned a0 = pd[base + 0], a1 = pd[base + 1];
        const unsigned a2 = pd[base + 2], a3 = pd[base + 3];
        const unsigned x0 = __shfl_xor(a0, 32), x1 = __shfl_xor(a1, 32);
        const unsigned x2 = __shfl_xor(a2, 32), x3 = __shfl_xor(a3, 32);
        const unsigned w0 = hi ? x2 : a0;
        const unsigned w1 = hi ? x3 : a1;
        const unsigned w2 = hi ? a2 : x0;
        const unsigned w3 = hi ? a3 : x1;
        union { u32x4 u; bf16x8 v; } cv;
        cv.u = (u32x4){w0, w1, w2, w3};
        const bf16x8 pa = cv.v;
        const int kc = k0 + tt * 32 + c * 16;
        const __bf16* Vp = &V[(size_t)l31 * S_LEN + kc + hi * 8];
        accO[0] = MFMA32(pa, *reinterpret_cast<const bf16x8*>(Vp), accO[0]);
        accO[1] = MFMA32(pa, *reinterpret_cast<const bf16x8*>(Vp + 32 * S_LEN), accO[1]);
      }
    }
  }

  // ---- epilogue: normalize and store ----
  const float inv = 1.0f / l_run;   // per q = l31
  const int b = bh >> 4, h = bh & 15;
#pragma unroll
  for (int r = 0; r < 16; ++r) {
    const int qrow = (r & 3) + ((r >> 2) << 3) + hi * 4;
    const float invr = __shfl(inv, qrow);
    const int qo = q0 + qrow;
    __bf16* Op = &Ob[((size_t)(b * S_LEN + qo)) * DMODEL + h * HDK + l31];
    Op[0] = (__bf16)(accO[0][r] * invr);
    Op[32] = (__bf16)(accO[1][r] * invr);
  }
}

// ---------------- output projection (f32 out) ----------------
__global__ __launch_bounds__(256) void k_oproj(
    const __bf16* __restrict__ Ob, const __bf16* __restrict__ Wob,
    float* __restrict__ out) {
  const int m0 = blockIdx.x * 64;
  const int n0 = blockIdx.y * 64;
  const int t = threadIdx.x;
  const int lane = t & 63;
  const int w = t >> 6;
  const int wm = (w >> 1) * 32;
  const int wn = (w & 1) * 32;
  const int l15 = lane & 15, lhi = lane >> 4;

  __shared__ __align__(16) __bf16 As[64 * 32];
  __shared__ __align__(16) __bf16 Bs[64 * 32];

  const f32x4 z4 = {0.f, 0.f, 0.f, 0.f};
  f32x4 acc[2][2] = {{z4, z4}, {z4, z4}};

  const __bf16* gA = Ob + (size_t)(m0 + (t >> 2)) * DMODEL + (t & 3) * 8;
  const __bf16* gB = Wob + (size_t)(n0 + (t >> 2)) * DMODEL + (t & 3) * 8;
  const int wr = swz32(t >> 2, t & 3);
  const int a0o = swz32(wm + l15, lhi), a1o = swz32(wm + 16 + l15, lhi);
  const int b0o = swz32(wn + l15, lhi), b1o = swz32(wn + 16 + l15, lhi);

  for (int k0 = 0; k0 < DMODEL; k0 += 32) {
    const bf16x8 ta = *reinterpret_cast<const bf16x8*>(gA + k0);
    const bf16x8 tb = *reinterpret_cast<const bf16x8*>(gB + k0);
    __syncthreads();
    *reinterpret_cast<bf16x8*>(&As[wr]) = ta;
    *reinterpret_cast<bf16x8*>(&Bs[wr]) = tb;
    __syncthreads();
    const bf16x8 a0 = *reinterpret_cast<const bf16x8*>(&As[a0o]);
    const bf16x8 a1 = *reinterpret_cast<const bf16x8*>(&As[a1o]);
    const bf16x8 b0 = *reinterpret_cast<const bf16x8*>(&Bs[b0o]);
    const bf16x8 b1 = *reinterpret_cast<const bf16x8*>(&Bs[b1o]);
    acc[0][0] = MFMA16(a0, b0, acc[0][0]);
    acc[0][1] = MFMA16(a0, b1, acc[0][1]);
    acc[1][0] = MFMA16(a1, b0, acc[1][0]);
    acc[1][1] = MFMA16(a1, b1, acc[1][1]);
  }

#pragma unroll
  for (int mi = 0; mi < 2; ++mi) {
#pragma unroll
    for (int ni = 0; ni < 2; ++ni) {
      const int e = n0 + wn + ni * 16 + l15;
#pragma unroll
      for (int r = 0; r < 4; ++r) {
        const int m = m0 + wm + mi * 16 + lhi * 4 + r;
        out[(size_t)m * DMODEL + e] = acc[mi][ni][r];
      }
    }
  }
}

extern "C" void kernel_launch(void* const* d_in, const int* in_sizes, int n_in,
                              void* d_out, int out_size, void* d_ws, size_t ws_size,
                              hipStream_t stream) {
  const float* x = (const float*)d_in[0];
  const int* tpos = (const int*)d_in[1];
  const float* Wq = (const float*)d_in[2];
  const float* Wk = (const float*)d_in[3];
  const float* Wv = (const float*)d_in[4];
  const float* Wo = (const float*)d_in[5];
  float* out = (float*)d_out;

  __bf16* ws = (__bf16*)d_ws;
  __bf16* Xb = ws;                    // 4096x1024
  __bf16* Wqb = Xb + 4194304;         // 1024x1024
  __bf16* Wkb = Wqb + 1048576;
  __bf16* Wvb = Wkb + 1048576;
  __bf16* Wob = Wvb + 1048576;
  __bf16* Qr = Wob + 1048576;         // [2][16][2048][64]
  __bf16* Kr = Qr + 4194304;
  __bf16* Vt = Kr + 4194304;          // [2][16][64][2048]
  __bf16* Ob = Vt + 4194304;          // 4096x1024

  k_cvt<<<4096, 256, 0, stream>>>(x, Xb, 1048576);
  k_cvt<<<1024, 256, 0, stream>>>(Wq, Wqb, 262144);
  k_cvt<<<1024, 256, 0, stream>>>(Wk, Wkb, 262144);
  k_cvt<<<1024, 256, 0, stream>>>(Wv, Wvb, 262144);
  k_cvt<<<1024, 256, 0, stream>>>(Wo, Wob, 262144);

  dim3 g1(64, 16, 3);
  k_qkv<<<g1, 256, 0, stream>>>(Xb, Wqb, Wkb, Wvb, tpos, Qr, Kr, Vt);

  k_attn<<<512, 256, 0, stream>>>(Qr, Kr, Vt, Ob);

  dim3 g2(64, 16);
  k_oproj<<<g2, 256, 0, stream>>>(Ob, Wob, out);
}

// Round 6
// 153.210 us; speedup vs baseline: 2.0861x; 1.4832x over previous
//
#include <hip/hip_runtime.h>
#include <hip/hip_bf16.h>
#include <cstdint>
#include <cstddef>

#define S_LEN 2048
#define DMODEL 1024
#define NHEAD 16
#define HDK 64
#define LOG2E 1.44269504088896340736f

typedef __attribute__((ext_vector_type(8))) __bf16 bf16x8;
typedef __attribute__((ext_vector_type(4))) __bf16 bf16x4;
typedef __attribute__((ext_vector_type(4))) float f32x4;
typedef __attribute__((ext_vector_type(16))) float f32x16;
typedef __attribute__((ext_vector_type(4))) unsigned int u32x4;

#define MFMA16(a, b, c) __builtin_amdgcn_mfma_f32_16x16x32_bf16((a), (b), (c), 0, 0, 0)
#define MFMA32(a, b, c) __builtin_amdgcn_mfma_f32_32x32x16_bf16((a), (b), (c), 0, 0, 0)

// Fragment-tiled layouts (per (b,h) plane of S_LEN x 64):
//  QK-tile:  off(s,d) = ((((s>>5)*4 + (d>>4))*2 + ((d>>3)&1))*32 + (s&31))*8 + (d&7)
//            -> a 32-row K/Q fragment load is lane-stride 16B, fully dense.
//  V-tile:   off(s,d) = ((s>>4)*64 + d)*16 + (s&15)
//            -> a 16-k x 32-d V fragment load is one dense 1KB region.
__device__ __forceinline__ size_t qk_off(int s, int d) {
  return ((((size_t)(s >> 5) * 4 + (d >> 4)) * 2 + ((d >> 3) & 1)) * 32 + (s & 31)) * 8 + (d & 7);
}
__device__ __forceinline__ size_t v_off(int s, int d) {
  return ((size_t)(s >> 4) * 64 + d) * 16 + (s & 15);
}

// element-offset swizzle for [rows][32] bf16 tiles (row = 64B)
__device__ __forceinline__ int swz32(int row, int slot) {
  return row * 32 + ((slot ^ ((row >> 1) & 3)) << 3);
}

// pack two f32 -> one dword of 2 bf16 (lo = first)
__device__ __forceinline__ unsigned pk2(float a, float b) {
  union { __bf16 h[2]; unsigned u; } cv;
  cv.h[0] = (__bf16)a;
  cv.h[1] = (__bf16)b;
  return cv.u;
}

// ---------------- f32 -> bf16 convert ----------------
__global__ __launch_bounds__(256) void k_cvt(const float* __restrict__ src,
                                             __bf16* __restrict__ dst, int n4) {
  const int i = blockIdx.x * 256 + threadIdx.x;
  if (i >= n4) return;
  const float4 v = reinterpret_cast<const float4*>(src)[i];
  bf16x4 o = { (__bf16)v.x, (__bf16)v.y, (__bf16)v.z, (__bf16)v.w };
  reinterpret_cast<bf16x4*>(dst)[i] = o;
}

// ---------------- fused QKV projection + RoPE ----------------
// z=0: Q (rope, pre-scaled 1/8, QK-tiled)  z=1: K (rope, QK-tiled)  z=2: V (V-tiled)
__global__ __launch_bounds__(256) void k_qkv(
    const __bf16* __restrict__ Xb,
    const __bf16* __restrict__ Wqb, const __bf16* __restrict__ Wkb,
    const __bf16* __restrict__ Wvb, const int* __restrict__ tpos,
    __bf16* __restrict__ Qr, __bf16* __restrict__ Kr, __bf16* __restrict__ Vt) {
  const int z = blockIdx.z;
  const __bf16* W = (z == 0) ? Wqb : (z == 1) ? Wkb : Wvb;
  const int m0 = blockIdx.x * 64;
  const int n0 = blockIdx.y * 64;
  const int t = threadIdx.x;
  const int lane = t & 63;
  const int w = t >> 6;
  const int wm = (w >> 1) * 32;
  const int wn = (w & 1) * 32;
  const int l15 = lane & 15, lhi = lane >> 4;

  __shared__ __align__(16) __bf16 As[64 * 32];
  __shared__ __align__(16) __bf16 Bs[64 * 32];

  const f32x4 z4 = {0.f, 0.f, 0.f, 0.f};
  f32x4 acc[2][2] = {{z4, z4}, {z4, z4}};

  const __bf16* gA = Xb + (size_t)(m0 + (t >> 2)) * DMODEL + (t & 3) * 8;
  const __bf16* gB = W + (size_t)(n0 + (t >> 2)) * DMODEL + (t & 3) * 8;
  const int wr = swz32(t >> 2, t & 3);
  const int a0o = swz32(wm + l15, lhi), a1o = swz32(wm + 16 + l15, lhi);
  const int b0o = swz32(wn + l15, lhi), b1o = swz32(wn + 16 + l15, lhi);

  for (int k0 = 0; k0 < DMODEL; k0 += 32) {
    const bf16x8 ta = *reinterpret_cast<const bf16x8*>(gA + k0);
    const bf16x8 tb = *reinterpret_cast<const bf16x8*>(gB + k0);
    __syncthreads();
    *reinterpret_cast<bf16x8*>(&As[wr]) = ta;
    *reinterpret_cast<bf16x8*>(&Bs[wr]) = tb;
    __syncthreads();
    const bf16x8 a0 = *reinterpret_cast<const bf16x8*>(&As[a0o]);
    const bf16x8 a1 = *reinterpret_cast<const bf16x8*>(&As[a1o]);
    const bf16x8 b0 = *reinterpret_cast<const bf16x8*>(&Bs[b0o]);
    const bf16x8 b1 = *reinterpret_cast<const bf16x8*>(&Bs[b1o]);
    acc[0][0] = MFMA16(a0, b0, acc[0][0]);
    acc[0][1] = MFMA16(a0, b1, acc[0][1]);
    acc[1][0] = MFMA16(a1, b0, acc[1][0]);
    acc[1][1] = MFMA16(a1, b1, acc[1][1]);
  }

  const int b0r = m0 + wm;
#pragma unroll
  for (int mi = 0; mi < 2; ++mi) {
#pragma unroll
    for (int ni = 0; ni < 2; ++ni) {
      const int e = n0 + wn + ni * 16 + l15;
      const int h = e >> 6, dkI = e & 63;
      if (z < 2) {
        // RoPE: pair (2i, 2i+1), ang = pos * theta^(-2i/64)
        const float invf = exp2f(-(float)(dkI & ~1) * (13.287712379549449f / 64.0f));
        const float oscale = (z == 0) ? 0.125f : 1.0f;  // fold 1/sqrt(dk) into Q
        __bf16* Out = (z == 0) ? Qr : Kr;
#pragma unroll
        for (int r = 0; r < 4; ++r) {
          const int m = b0r + mi * 16 + lhi * 4 + r;
          const int bb = m >> 11, ss = m & (S_LEN - 1);
          const float pos = (float)tpos[m];
          const float ang = pos * invf;
          const float cs = cosf(ang), sn = sinf(ang);
          const float own = acc[mi][ni][r];
          const float par = __shfl_xor(own, 1);
          const float val = (dkI & 1) ? (par * sn + own * cs) : (own * cs - par * sn);
          Out[(size_t)(bb * NHEAD + h) * (S_LEN * HDK) + qk_off(ss, dkI)] =
              (__bf16)(val * oscale);
        }
      } else {
#pragma unroll
        for (int r = 0; r < 4; ++r) {
          const int m = b0r + mi * 16 + lhi * 4 + r;
          const int bb = m >> 11, ss = m & (S_LEN - 1);
          Vt[(size_t)(bb * NHEAD + h) * (S_LEN * HDK) + v_off(ss, dkI)] =
              (__bf16)acc[mi][ni][r];
        }
      }
    }
  }
}

// ---------------- causal flash attention (QBLK=32, 32x32 MFMA, LDS-free) ----------------
// Structure as Round 5 (verified correct). New: fragment-tiled K/Q/V loads (dense
// 1KB per instruction) + software pipeline (V loaded at iter top, K reloaded for
// next iter right after QK consumes it).
__global__ __launch_bounds__(256, 2) void k_attn(
    const __bf16* __restrict__ Qr, const __bf16* __restrict__ Kr,
    const __bf16* __restrict__ Vt, __bf16* __restrict__ Ob) {
  const int t = threadIdx.x, lane = t & 63, w = t >> 6;
  const int blk = blockIdx.x;
  const int qg = blk >> 5;               // 0..15, heavy-first
  const int bh = blk & 31;
  const int qtile = (15 - qg) * 4 + w;   // 0..63
  const int q0 = qtile * 32;
  const int l31 = lane & 31, hi = lane >> 5;

  const __bf16* Q = Qr + (size_t)bh * (S_LEN * HDK);
  const __bf16* K = Kr + (size_t)bh * (S_LEN * HDK);
  const __bf16* V = Vt + (size_t)bh * (S_LEN * HDK);

  // Q fragments: row q=l31, d = dc*16 + hi*8 + j  (tiled: dense, lane-stride 16B)
  bf16x8 qf[4];
#pragma unroll
  for (int dc = 0; dc < 4; ++dc)
    qf[dc] = *reinterpret_cast<const bf16x8*>(
        &Q[((((size_t)(q0 >> 5) * 4 + dc) * 2 + hi) * 32 + l31) * 8]);

  f32x16 accO[2] = {};
  float m_run = -3e30f, l_run = 0.0f;
  const int q = q0 + l31;
  const int kmax = q0 + 32;

  // preload K fragments for k0 = 0 (2 tiles of 32 rows x 4 d-chunks)
  bf16x8 kf[2][4];
#pragma unroll
  for (int tt = 0; tt < 2; ++tt)
#pragma unroll
    for (int dc = 0; dc < 4; ++dc)
      kf[tt][dc] = *reinterpret_cast<const bf16x8*>(
          &K[((((size_t)tt * 4 + dc) * 2 + hi) * 32 + l31) * 8]);

  for (int k0 = 0; k0 < kmax; k0 += 64) {
    // ---- prefetch V fragments for THIS iteration (window = QK + softmax) ----
    // vf[ttc][d0h]: k-chunk ttc*16, d = d0h*32 + l31, s = +hi*8+j  (dense 1KB)
    bf16x8 vf[4][2];
#pragma unroll
    for (int ttc = 0; ttc < 4; ++ttc) {
      const int kc = k0 + ttc * 16;
#pragma unroll
      for (int d0h = 0; d0h < 2; ++d0h)
        vf[ttc][d0h] = *reinterpret_cast<const bf16x8*>(
            &V[((size_t)(kc >> 4) * 64 + d0h * 32 + l31) * 16 + hi * 8]);
    }

    // ---- QK^T (swapped): two 32k x 32q tiles ----
    f32x16 sT0 = {}, sT1 = {};
#pragma unroll
    for (int dc = 0; dc < 4; ++dc) {
      sT0 = MFMA32(kf[0][dc], qf[dc], sT0);
      sT1 = MFMA32(kf[1][dc], qf[dc], sT1);
    }

    // ---- reload K fragments for NEXT iteration (window = softmax + PV) ----
    if (k0 + 64 < kmax) {
      const int kn = (k0 + 64) >> 5;
#pragma unroll
      for (int tt = 0; tt < 2; ++tt)
#pragma unroll
        for (int dc = 0; dc < 4; ++dc)
          kf[tt][dc] = *reinterpret_cast<const bf16x8*>(
              &K[((((size_t)(kn + tt) * 4 + dc) * 2 + hi) * 32 + l31) * 8]);
    }

    // ---- causal mask + in-register max ----
    const bool maskIt = (k0 + 63 > q0);
    float mx = -3e30f;
#pragma unroll
    for (int r = 0; r < 16; ++r) {
      float s0 = sT0[r], s1 = sT1[r];
      if (maskIt) {
        const int kb = (r & 3) + ((r >> 2) << 3) + hi * 4;
        if (k0 + kb > q) s0 = -3e30f;
        if (k0 + 32 + kb > q) s1 = -3e30f;
      }
      sT0[r] = s0;
      sT1[r] = s1;
      mx = fmaxf(mx, fmaxf(s0, s1));
    }
    mx = fmaxf(mx, __shfl_xor(mx, 32));

    // ---- defer-max: rescale only when max grew past threshold ----
    float sc = 1.0f;
    if (!__all(mx <= m_run + 8.0f)) {
      const float mn = fmaxf(m_run, mx);
      sc = exp2f((m_run - mn) * LOG2E);
      m_run = mn;
      float scA[16];
#pragma unroll
      for (int r = 0; r < 16; ++r)
        scA[r] = __shfl(sc, (r & 3) + ((r >> 2) << 3) + hi * 4);
#pragma unroll
      for (int dt = 0; dt < 2; ++dt)
#pragma unroll
        for (int r = 0; r < 16; ++r) accO[dt][r] *= scA[r];
    }

    // ---- exp + running sum + pack to bf16 dwords ----
    float rs = 0.0f;
    unsigned pd[16];
#pragma unroll
    for (int j = 0; j < 8; ++j) {
      const float p0 = exp2f((sT0[2 * j] - m_run) * LOG2E);
      const float p1 = exp2f((sT0[2 * j + 1] - m_run) * LOG2E);
      const float p2 = exp2f((sT1[2 * j] - m_run) * LOG2E);
      const float p3 = exp2f((sT1[2 * j + 1] - m_run) * LOG2E);
      rs += (p0 + p1) + (p2 + p3);
      pd[j] = pk2(p0, p1);
      pd[8 + j] = pk2(p2, p3);
    }
    rs += __shfl_xor(rs, 32);
    l_run = l_run * sc + rs;

    // ---- PV: build A-frags via cross-half shfl + select, accumulate ----
#pragma unroll
    for (int tt = 0; tt < 2; ++tt) {
#pragma unroll
      for (int c = 0; c < 2; ++c) {
        const int base = tt * 8 + c * 4;
        const unsigned a0 = pd[base + 0], a1 = pd[base + 1];
        const unsigned a2 = pd[base + 2], a3 = pd[base + 3];
        const unsigned x0 = __shfl_xor(a0, 32), x1 = __shfl_xor(a1, 32);
        const unsigned x2 = __shfl_xor(a2, 32), x3 = __shfl_xor(a3, 32);
        const unsigned w0 = hi ? x2 : a0;
        const unsigned w1 = hi ? x3 : a1;
        const unsigned w2 = hi ? a2 : x0;
        const unsigned w3 = hi ? a3 : x1;
        union { u32x4 u; bf16x8 v; } cv;
        cv.u = (u32x4){w0, w1, w2, w3};
        const bf16x8 pa = cv.v;
        const int ttc = tt * 2 + c;
        accO[0] = MFMA32(pa, vf[ttc][0], accO[0]);
        accO[1] = MFMA32(pa, vf[ttc][1], accO[1]);
      }
    }
  }

  // ---- epilogue: normalize and store ----
  const float inv = 1.0f / l_run;   // per q = l31
  const int b = bh >> 4, h = bh & 15;
#pragma unroll
  for (int r = 0; r < 16; ++r) {
    const int qrow = (r & 3) + ((r >> 2) << 3) + hi * 4;
    const float invr = __shfl(inv, qrow);
    const int qo = q0 + qrow;
    __bf16* Op = &Ob[((size_t)(b * S_LEN + qo)) * DMODEL + h * HDK + l31];
    Op[0] = (__bf16)(accO[0][r] * invr);
    Op[32] = (__bf16)(accO[1][r] * invr);
  }
}

// ---------------- output projection (f32 out) ----------------
__global__ __launch_bounds__(256) void k_oproj(
    const __bf16* __restrict__ Ob, const __bf16* __restrict__ Wob,
    float* __restrict__ out) {
  const int m0 = blockIdx.x * 64;
  const int n0 = blockIdx.y * 64;
  const int t = threadIdx.x;
  const int lane = t & 63;
  const int w = t >> 6;
  const int wm = (w >> 1) * 32;
  const int wn = (w & 1) * 32;
  const int l15 = lane & 15, lhi = lane >> 4;

  __shared__ __align__(16) __bf16 As[64 * 32];
  __shared__ __align__(16) __bf16 Bs[64 * 32];

  const f32x4 z4 = {0.f, 0.f, 0.f, 0.f};
  f32x4 acc[2][2] = {{z4, z4}, {z4, z4}};

  const __bf16* gA = Ob + (size_t)(m0 + (t >> 2)) * DMODEL + (t & 3) * 8;
  const __bf16* gB = Wob + (size_t)(n0 + (t >> 2)) * DMODEL + (t & 3) * 8;
  const int wr = swz32(t >> 2, t & 3);
  const int a0o = swz32(wm + l15, lhi), a1o = swz32(wm + 16 + l15, lhi);
  const int b0o = swz32(wn + l15, lhi), b1o = swz32(wn + 16 + l15, lhi);

  for (int k0 = 0; k0 < DMODEL; k0 += 32) {
    const bf16x8 ta = *reinterpret_cast<const bf16x8*>(gA + k0);
    const bf16x8 tb = *reinterpret_cast<const bf16x8*>(gB + k0);
    __syncthreads();
    *reinterpret_cast<bf16x8*>(&As[wr]) = ta;
    *reinterpret_cast<bf16x8*>(&Bs[wr]) = tb;
    __syncthreads();
    const bf16x8 a0 = *reinterpret_cast<const bf16x8*>(&As[a0o]);
    const bf16x8 a1 = *reinterpret_cast<const bf16x8*>(&As[a1o]);
    const bf16x8 b0 = *reinterpret_cast<const bf16x8*>(&Bs[b0o]);
    const bf16x8 b1 = *reinterpret_cast<const bf16x8*>(&Bs[b1o]);
    acc[0][0] = MFMA16(a0, b0, acc[0][0]);
    acc[0][1] = MFMA16(a0, b1, acc[0][1]);
    acc[1][0] = MFMA16(a1, b0, acc[1][0]);
    acc[1][1] = MFMA16(a1, b1, acc[1][1]);
  }

#pragma unroll
  for (int mi = 0; mi < 2; ++mi) {
#pragma unroll
    for (int ni = 0; ni < 2; ++ni) {
      const int e = n0 + wn + ni * 16 + l15;
#pragma unroll
      for (int r = 0; r < 4; ++r) {
        const int m = m0 + wm + mi * 16 + lhi * 4 + r;
        out[(size_t)m * DMODEL + e] = acc[mi][ni][r];
      }
    }
  }
}

extern "C" void kernel_launch(void* const* d_in, const int* in_sizes, int n_in,
                              void* d_out, int out_size, void* d_ws, size_t ws_size,
                              hipStream_t stream) {
  const float* x = (const float*)d_in[0];
  const int* tpos = (const int*)d_in[1];
  const float* Wq = (const float*)d_in[2];
  const float* Wk = (const float*)d_in[3];
  const float* Wv = (const float*)d_in[4];
  const float* Wo = (const float*)d_in[5];
  float* out = (float*)d_out;

  __bf16* ws = (__bf16*)d_ws;
  __bf16* Xb = ws;                    // 4096x1024
  __bf16* Wqb = Xb + 4194304;         // 1024x1024
  __bf16* Wkb = Wqb + 1048576;
  __bf16* Wvb = Wkb + 1048576;
  __bf16* Wob = Wvb + 1048576;
  __bf16* Qr = Wob + 1048576;         // [2][16] QK-tiled planes
  __bf16* Kr = Qr + 4194304;
  __bf16* Vt = Kr + 4194304;          // [2][16] V-tiled planes
  __bf16* Ob = Vt + 4194304;          // 4096x1024

  k_cvt<<<4096, 256, 0, stream>>>(x, Xb, 1048576);
  k_cvt<<<1024, 256, 0, stream>>>(Wq, Wqb, 262144);
  k_cvt<<<1024, 256, 0, stream>>>(Wk, Wkb, 262144);
  k_cvt<<<1024, 256, 0, stream>>>(Wv, Wvb, 262144);
  k_cvt<<<1024, 256, 0, stream>>>(Wo, Wob, 262144);

  dim3 g1(64, 16, 3);
  k_qkv<<<g1, 256, 0, stream>>>(Xb, Wqb, Wkb, Wvb, tpos, Qr, Kr, Vt);

  k_attn<<<512, 256, 0, stream>>>(Qr, Kr, Vt, Ob);

  dim3 g2(64, 16);
  k_oproj<<<g2, 256, 0, stream>>>(Ob, Wob, out);
}